// Round 1
// baseline (18.468 us; speedup 1.0000x reference)
//
#include <hip/hip_runtime.h>

// Grouped batched matmul: y[t] = x[t] @ W[seg(t)] + b[seg(t)]
// x: [TOTAL, 32] f32, W: [N, 32, 32] f32, b: [N, 32] f32, cnt: [N] i32
// One network per block; 128 threads (2 waves); register tile 8p x 4o.

#define BLK 128

__global__ __launch_bounds__(BLK) void mnl_kernel(
    const float* __restrict__ x,
    const float* __restrict__ w,
    const float* __restrict__ bias,
    const int* __restrict__ cnt,
    float* __restrict__ y)
{
    __shared__ float xT[32][BLK];   // xT[i][p] : transposed x chunk (16 KB)
    __shared__ float Wl[32][32];    // W row-major [in][out] (4 KB)
    __shared__ float Bl[32];
    __shared__ int   red[BLK];

    const int n = blockIdx.x;
    const int t = threadIdx.x;

    // ---- exclusive prefix sum: segment base for this network ----
    int s = 0;
    for (int j = t; j < n; j += BLK) s += cnt[j];
    red[t] = s;
    __syncthreads();
    #pragma unroll
    for (int off = BLK / 2; off > 0; off >>= 1) {
        if (t < off) red[t] += red[t + off];
        __syncthreads();
    }
    const int base  = red[0];
    const int count = cnt[n];

    // ---- stage W and bias (before first chunk barrier) ----
    {
        const float4* wg  = reinterpret_cast<const float4*>(w + (size_t)n * 1024);
        float4*       wl4 = reinterpret_cast<float4*>(&Wl[0][0]);
        wl4[t]       = wg[t];
        wl4[t + BLK] = wg[t + BLK];
        if (t < 8) {
            reinterpret_cast<float4*>(Bl)[t] =
                reinterpret_cast<const float4*>(bias + (size_t)n * 32)[t];
        }
    }

    const int o0 = (t & 7) * 4;   // output tile: 4 consecutive outputs
    const int p0 = (t >> 3) * 8;  // point tile: 8 consecutive points

    for (int pc = 0; pc < count; pc += BLK) {
        // ---- load one x row per thread (row = one 128B cache line) ----
        const int p = pc + t;
        float4 rr[8];
        if (p < count) {
            const float4* xg = reinterpret_cast<const float4*>(x + (size_t)(base + p) * 32);
            #pragma unroll
            for (int k = 0; k < 8; ++k) rr[k] = xg[k];
        } else {
            #pragma unroll
            for (int k = 0; k < 8; ++k) rr[k] = make_float4(0.f, 0.f, 0.f, 0.f);
        }

        __syncthreads();  // previous chunk's xT reads done (also orders W staging on iter 0)

        // ---- transposed write: consecutive lanes -> consecutive addresses ----
        #pragma unroll
        for (int k = 0; k < 8; ++k) {
            xT[4 * k + 0][t] = rr[k].x;
            xT[4 * k + 1][t] = rr[k].y;
            xT[4 * k + 2][t] = rr[k].z;
            xT[4 * k + 3][t] = rr[k].w;
        }

        __syncthreads();

        // ---- compute: 8x4 register tile ----
        float acc[8][4] = {};
        #pragma unroll
        for (int i = 0; i < 32; ++i) {
            const float4 xa = *reinterpret_cast<const float4*>(&xT[i][p0]);
            const float4 xb = *reinterpret_cast<const float4*>(&xT[i][p0 + 4]);
            const float4 wv = *reinterpret_cast<const float4*>(&Wl[i][o0]);
            const float xs[8] = {xa.x, xa.y, xa.z, xa.w, xb.x, xb.y, xb.z, xb.w};
            const float ws[4] = {wv.x, wv.y, wv.z, wv.w};
            #pragma unroll
            for (int pp = 0; pp < 8; ++pp)
                #pragma unroll
                for (int oo = 0; oo < 4; ++oo)
                    acc[pp][oo] = fmaf(xs[pp], ws[oo], acc[pp][oo]);
        }

        // ---- epilogue: bias add + coalesced float4 stores ----
        const float4 b4 = *reinterpret_cast<const float4*>(&Bl[o0]);
        #pragma unroll
        for (int pp = 0; pp < 8; ++pp) {
            const int prow = pc + p0 + pp;
            if (prow < count) {
                float4 o;
                o.x = acc[pp][0] + b4.x;
                o.y = acc[pp][1] + b4.y;
                o.z = acc[pp][2] + b4.z;
                o.w = acc[pp][3] + b4.w;
                *reinterpret_cast<float4*>(&y[(size_t)(base + prow) * 32 + o0]) = o;
            }
        }
    }
}

extern "C" void kernel_launch(void* const* d_in, const int* in_sizes, int n_in,
                              void* d_out, int out_size, void* d_ws, size_t ws_size,
                              hipStream_t stream) {
    const float* x    = (const float*)d_in[0];
    const float* w    = (const float*)d_in[1];
    const float* bias = (const float*)d_in[2];
    const int*   cnt  = (const int*)d_in[3];
    float*       y    = (float*)d_out;
    const int n_nets = in_sizes[3];

    mnl_kernel<<<n_nets, BLK, 0, stream>>>(x, w, bias, cnt, y);
}